// Round 17
// baseline (167.381 us; speedup 1.0000x reference)
//
#include <hip/hip_runtime.h>

#define B_ 8
#define C_ 512
#define N_ 2048
#define O_ 256   // C/2

typedef unsigned short u16;
typedef unsigned char u8;
typedef unsigned int uint;
typedef float f32x4 __attribute__((ext_vector_type(4)));
typedef int i32x8 __attribute__((ext_vector_type(8)));

#define AS1 __attribute__((address_space(1)))
#define AS3 __attribute__((address_space(3)))

__device__ __forceinline__ u16 f2bf(float f) {
  union { float f; unsigned u; } v; v.f = f;
  return (u16)((v.u + 0x7fffu + ((v.u >> 16) & 1u)) >> 16);  // RNE
}
__device__ __forceinline__ float bf2f(u16 h) {
  union { uint u; float f; } v; v.u = ((uint)h) << 16; return v.f;
}
// pack 4 floats -> 4 OCP e4m3 bytes (HW cvt, RNE)
__device__ __forceinline__ uint pk4_e4m3(float a, float b, float c, float d) {
  int r = __builtin_amdgcn_cvt_pk_fp8_f32(a, b, 0, false);
  r = __builtin_amdgcn_cvt_pk_fp8_f32(c, d, r, true);
  return (uint)r;
}

// ---------------------------------------------------------------------------
// 128x128 MX-fp8 tile main loop, K=128/instr, unit scales (verified r5-r7).
// Rows are lda/ldb BYTES. XOR 16B-group swizzle (row&7) on stage + read.
// acc[i][j]: row = wm+i*16+quad*4+rr, col = wn+j*16+(lane&15)
// Single-buffered 3-sync schedule: measured BEST (169 R0 / 167 R9 / 163 R14)
// vs explicit dbuf (177 R1) -- implicit multi-block overlap beats source
// pipelining. 16B LDS-read per MFMA.
// ---------------------------------------------------------------------------
union MxFrag { i32x8 v; uint4 q[2]; };

__device__ __forceinline__ void mx_mainloop(
    const u8* __restrict__ Ag, int lda,
    const u8* __restrict__ Bg, int ldb, int K,
    u8 (&As)[128][128], u8 (&Bs)[128][128], f32x4 (&acc)[4][4])
{
  const int t = threadIdx.x;
  const int lane = t & 63;
  const int w = t >> 6;
  const int wm = (w >> 1) * 64, wn = (w & 1) * 64;
  const int lrow = lane & 15, quad = lane >> 4;
  const int swz = lrow & 7;
  const int r8 = lane >> 3;
  const int gsrc = (lane & 7) ^ r8;

  for (int k0 = 0; k0 < K; k0 += 128) {
#pragma unroll
    for (int i = 0; i < 4; i++) {
      int row = i * 32 + w * 8;
      __builtin_amdgcn_global_load_lds(
          (const AS1 uint*)(Ag + (size_t)(row + r8) * lda + k0 + gsrc * 16),
          (AS3 uint*)(&As[row][0]), 16, 0, 0);
      __builtin_amdgcn_global_load_lds(
          (const AS1 uint*)(Bg + (size_t)(row + r8) * ldb + k0 + gsrc * 16),
          (AS3 uint*)(&Bs[row][0]), 16, 0, 0);
    }
    __syncthreads();
    const int g0 = (quad * 2) ^ swz, g1 = (quad * 2 + 1) ^ swz;
    MxFrag af[4], bfr[4];
#pragma unroll
    for (int i = 0; i < 4; i++) {
      const u8* rp = &As[wm + i * 16 + lrow][0];
      af[i].q[0] = *(const uint4*)(rp + g0 * 16);
      af[i].q[1] = *(const uint4*)(rp + g1 * 16);
    }
#pragma unroll
    for (int j = 0; j < 4; j++) {
      const u8* rp = &Bs[wn + j * 16 + lrow][0];
      bfr[j].q[0] = *(const uint4*)(rp + g0 * 16);
      bfr[j].q[1] = *(const uint4*)(rp + g1 * 16);
    }
#pragma unroll
    for (int i = 0; i < 4; i++)
#pragma unroll
      for (int j = 0; j < 4; j++)
        acc[i][j] = __builtin_amdgcn_mfma_scale_f32_16x16x128_f8f6f4(
            af[i].v, bfr[j].v, acc[i][j],
            0, 0,                      // fp8 e4m3 / fp8 e4m3
            0, 0x7f7f7f7f,             // A scales = 1.0
            0, 0x7f7f7f7f);            // B scales = 1.0
    __syncthreads();
  }
}

// ---------------------------------------------------------------------------
// 512-thread variant: 256(A-rows) x 128(B-rows) tile, 8 waves = 4m x 2n,
// wave tile 64x64 (same per-wave VGPR/intensity as mx_mainloop). Used by
// attn_s R15 retile: halves per-output prologue/epilogue/barriers and Q
// staging. Same swizzle conventions (row&7 == lrow&7 preserved: wm,wn
// multiples of 64; slab rows multiples of 8).
// ---------------------------------------------------------------------------
__device__ __forceinline__ void mx_mainloop_512(
    const u8* __restrict__ Ag, int lda,
    const u8* __restrict__ Bg, int ldb, int K,
    u8 (&As)[256][128], u8 (&Bs)[128][128], f32x4 (&acc)[4][4])
{
  const int t = threadIdx.x;
  const int lane = t & 63;
  const int w = t >> 6;                  // 0..7
  const int wm = (w & 3) * 64, wn = (w >> 2) * 64;
  const int lrow = lane & 15, quad = lane >> 4;
  const int swz = lrow & 7;
  const int r8 = lane >> 3;
  const int gsrc = (lane & 7) ^ r8;

  for (int k0 = 0; k0 < K; k0 += 128) {
#pragma unroll
    for (int s = 0; s < 4; s++) {        // A: 256 rows, 4 slabs/wave
      int row = (w * 4 + s) * 8;
      __builtin_amdgcn_global_load_lds(
          (const AS1 uint*)(Ag + (size_t)(row + r8) * lda + k0 + gsrc * 16),
          (AS3 uint*)(&As[row][0]), 16, 0, 0);
    }
#pragma unroll
    for (int s = 0; s < 2; s++) {        // B: 128 rows, 2 slabs/wave
      int row = (w * 2 + s) * 8;
      __builtin_amdgcn_global_load_lds(
          (const AS1 uint*)(Bg + (size_t)(row + r8) * ldb + k0 + gsrc * 16),
          (AS3 uint*)(&Bs[row][0]), 16, 0, 0);
    }
    __syncthreads();
    const int g0 = (quad * 2) ^ swz, g1 = (quad * 2 + 1) ^ swz;
    MxFrag af[4], bfr[4];
#pragma unroll
    for (int i = 0; i < 4; i++) {
      const u8* rp = &As[wm + i * 16 + lrow][0];
      af[i].q[0] = *(const uint4*)(rp + g0 * 16);
      af[i].q[1] = *(const uint4*)(rp + g1 * 16);
    }
#pragma unroll
    for (int j = 0; j < 4; j++) {
      const u8* rp = &Bs[wn + j * 16 + lrow][0];
      bfr[j].q[0] = *(const uint4*)(rp + g0 * 16);
      bfr[j].q[1] = *(const uint4*)(rp + g1 * 16);
    }
#pragma unroll
    for (int i = 0; i < 4; i++)
#pragma unroll
      for (int j = 0; j < 4; j++)
        acc[i][j] = __builtin_amdgcn_mfma_scale_f32_16x16x128_f8f6f4(
            af[i].v, bfr[j].v, acc[i][j],
            0, 0, 0, 0x7f7f7f7f, 0, 0x7f7f7f7f);
    __syncthreads();
  }
}

// ---------------------------------------------------------------------------
// prep: ONE dispatch does (a) x (B,C,N) f32 -> xT8 (B,N,C) fp8 via 64x64 LDS
// tile transpose (blocks 0..2047), (b) W fp32 -> fp8 (blocks 2048..2559),
// (c) rowsum zero-init. grid 2560 x 256 thr.
// ---------------------------------------------------------------------------
__global__ __launch_bounds__(256) void prep_kernel(
    const float* __restrict__ x,
    const float* __restrict__ Wq, const float* __restrict__ Wk,
    const float* __restrict__ Wv,
    u8* __restrict__ xT8, u8* __restrict__ Wq8, u8* __restrict__ Wk8,
    u8* __restrict__ Wv8, float* __restrict__ rowsum)
{
  __shared__ u16 tile[64][72];
  const int bid = blockIdx.x;
  const int t = threadIdx.x;
  if (bid < 2048) {
    int b = bid >> 8;
    int n0 = (bid & 31) * 64;
    int c0 = ((bid >> 5) & 7) * 64;
    const float* src = x + (size_t)b * C_ * N_ + (size_t)c0 * N_ + n0;
    int r = t >> 4;            // 0..15
    int f4 = (t & 15) * 4;     // 0..60 (n offset)
#pragma unroll
    for (int i = 0; i < 4; i++) {
      int c = r + 16 * i;
      float4 v = *(const float4*)(src + (size_t)c * N_ + f4);
      tile[f4 + 0][c] = f2bf(v.x);
      tile[f4 + 1][c] = f2bf(v.y);
      tile[f4 + 2][c] = f2bf(v.z);
      tile[f4 + 3][c] = f2bf(v.w);
    }
    __syncthreads();
    u8* dst = xT8 + (size_t)b * N_ * C_ + (size_t)n0 * C_ + c0;
    int n = t >> 2;            // 0..63
    int cc = (t & 3) * 16;     // 0,16,32,48
    uint4 d;
    d.x = pk4_e4m3(bf2f(tile[n][cc + 0]), bf2f(tile[n][cc + 1]),
                   bf2f(tile[n][cc + 2]), bf2f(tile[n][cc + 3]));
    d.y = pk4_e4m3(bf2f(tile[n][cc + 4]), bf2f(tile[n][cc + 5]),
                   bf2f(tile[n][cc + 6]), bf2f(tile[n][cc + 7]));
    d.z = pk4_e4m3(bf2f(tile[n][cc + 8]), bf2f(tile[n][cc + 9]),
                   bf2f(tile[n][cc + 10]), bf2f(tile[n][cc + 11]));
    d.w = pk4_e4m3(bf2f(tile[n][cc + 12]), bf2f(tile[n][cc + 13]),
                   bf2f(tile[n][cc + 14]), bf2f(tile[n][cc + 15]));
    *(uint4*)(dst + (size_t)n * C_ + cc) = d;
  } else {
    int gid = (bid - 2048) * 256 + t;      // 0..131071, 4 elems each
    const float* src; u8* dst; int o;
    if (gid < 32768)      { src = Wq; dst = Wq8; o = gid; }
    else if (gid < 65536) { src = Wk; dst = Wk8; o = gid - 32768; }
    else                  { src = Wv; dst = Wv8; o = gid - 65536; }
    float4 v = *(const float4*)(src + (size_t)o * 4);
    *(uint*)(dst + (size_t)o * 4) = pk4_e4m3(v.x, v.y, v.z, v.w);
    if (gid < 4096) {
      float4 z = {0.f, 0.f, 0.f, 0.f};
      *(float4*)(rowsum + gid * 4) = z;
    }
  }
}

// ---------------------------------------------------------------------------
// Unified projection (MX-fp8, K=512, 4 staging iters). grid 1024 = (16,8,8):
// XCD swizzle: b = L&7 pins batch->XCD.
//   sub 0..3: Q/K o-tiles -- transposed gemm A=W rows o, B=xT8 rows n,
//           rr walks o -> fp8 dword stores Qt8/Kt8[n][o..o+4)
//   sub 4..7: V c-tiles   -- A=xT8 rows n, B=Wv rows c,
//           rr walks n -> fp8 dword stores V8[c][n..n+4)
// ---------------------------------------------------------------------------
__global__ __launch_bounds__(256) void proj_all_kernel(
    const u8* __restrict__ xT8,
    const u8* __restrict__ Wq8, const float* __restrict__ bq,
    const u8* __restrict__ Wk8, const float* __restrict__ bk,
    const u8* __restrict__ Wv8, const float* __restrict__ bv,
    u8* __restrict__ Qt8, u8* __restrict__ Kt8, u8* __restrict__ V8)
{
  __shared__ __align__(16) u8 As[128][128], Bs[128][128];
  const int Lf = blockIdx.x +
                 (int)(gridDim.x * (blockIdx.y + gridDim.y * blockIdx.z));
  const int b = Lf & 7;                  // XCD = dispatch%8 heuristic
  const int rem = Lf >> 3;               // 0..127
  const int n0 = (rem & 15) * 128;
  const int sub = rem >> 4;              // 0..7
  const u8* xTb = xT8 + (size_t)b * N_ * C_ + (size_t)n0 * C_;

  const f32x4 zero = {0.f, 0.f, 0.f, 0.f};
  f32x4 acc[4][4];
#pragma unroll
  for (int i = 0; i < 4; i++)
#pragma unroll
    for (int j = 0; j < 4; j++) acc[i][j] = zero;

  const int lane = threadIdx.x & 63;
  const int w = threadIdx.x >> 6;
  const int wm = (w >> 1) * 64, wn = (w & 1) * 64;
  const int quad = lane >> 4, lcol = lane & 15;

  if (sub < 4) {
    const int isK = sub >> 1;
    const int o0 = (sub & 1) * 128;
    const u8* Wg = (isK ? Wk8 : Wq8) + (size_t)o0 * C_;
    const float* bias = isK ? bk : bq;
    u8* outp = (isK ? Kt8 : Qt8) + (size_t)b * N_ * O_;

    mx_mainloop(Wg, C_, xTb, C_, C_, As, Bs, acc);

#pragma unroll
    for (int i = 0; i < 4; i++) {
      int obase = o0 + wm + i * 16 + quad * 4;
      float4 bb = *(const float4*)(bias + obase);
#pragma unroll
      for (int j = 0; j < 4; j++) {
        int n = n0 + wn + j * 16 + lcol;
        uint d = pk4_e4m3(acc[i][j][0] + bb.x, acc[i][j][1] + bb.y,
                          acc[i][j][2] + bb.z, acc[i][j][3] + bb.w);
        *(uint*)(outp + (size_t)n * O_ + obase) = d;
      }
    }
  } else {
    const int c0 = (sub - 4) * 128;
    const u8* Wg = Wv8 + (size_t)c0 * C_;
    u8* outp = V8 + (size_t)b * C_ * N_;

    mx_mainloop(xTb, C_, Wg, C_, C_, As, Bs, acc);

#pragma unroll
    for (int j = 0; j < 4; j++) {
      int c = c0 + wn + j * 16 + lcol;
      float bb = bv[c];
#pragma unroll
      for (int i = 0; i < 4; i++) {
        int nbase = n0 + wm + i * 16 + quad * 4;
        uint d = pk4_e4m3(acc[i][j][0] + bb, acc[i][j][1] + bb,
                          acc[i][j][2] + bb, acc[i][j][3] + bb);
        *(uint*)(outp + (size_t)c * N_ + nbase) = d;
      }
    }
  }
}

// ---------------------------------------------------------------------------
// P (B,N,N) fp8 = exp(scale * Q.K^T), MX-fp8 (K=256). R15 retile: 512-thr
// blocks, 256m x 128n tile (was 128x128) -- halves per-output prologue/
// epilogue/barrier count and Q staging; per-wave working set unchanged.
// Transposed gemm T[m][n] = K.Q^T: rr walks m -> dword stores into P[n][:].
// rowsum via quad-reduce + atomics (same total sum per n, order-independent).
// grid 1024 = (8,16,8); b = L&7 XCD-pins batch.
// ---------------------------------------------------------------------------
__global__ __launch_bounds__(512) void attn_s_kernel(
    const u8* __restrict__ Qt8, const u8* __restrict__ Kt8,
    u8* __restrict__ P, float* __restrict__ rowsum)
{
  __shared__ __align__(16) u8 As[256][128], Bs[128][128];   // 48 KB
  const int Lf = blockIdx.x +
                 (int)(gridDim.x * (blockIdx.y + gridDim.y * blockIdx.z));
  const int b = Lf & 7;
  const int rem = Lf >> 3;               // 0..127
  const int m0 = (rem & 7) * 256;
  const int n0 = (rem >> 3) * 128;
  const u8* Ag = Kt8 + (size_t)b * N_ * O_ + (size_t)m0 * O_;   // rows m
  const u8* Bg = Qt8 + (size_t)b * N_ * O_ + (size_t)n0 * O_;   // rows n

  const f32x4 zero = {0.f, 0.f, 0.f, 0.f};
  f32x4 acc[4][4];
#pragma unroll
  for (int i = 0; i < 4; i++)
#pragma unroll
    for (int j = 0; j < 4; j++) acc[i][j] = zero;

  mx_mainloop_512(Ag, O_, Bg, O_, O_, As, Bs, acc);

  u8* Pp = P + (size_t)b * N_ * N_;
  float* rs = rowsum + (size_t)b * N_;
  const int lane = threadIdx.x & 63;
  const int w = threadIdx.x >> 6;        // 0..7
  const int wm = (w & 3) * 64, wn = (w >> 2) * 64;
  const int quad = lane >> 4, lcol = lane & 15;

  float partial[4];
#pragma unroll
  for (int j = 0; j < 4; j++) partial[j] = 0.f;

#pragma unroll
  for (int j = 0; j < 4; j++) {
    int n = n0 + wn + j * 16 + lcol;
#pragma unroll
    for (int i = 0; i < 4; i++) {
      int mbase = m0 + wm + i * 16 + quad * 4;
      float p0 = __expf(acc[i][j][0] * 0.0625f);   // scale = 1/sqrt(256)
      float p1 = __expf(acc[i][j][1] * 0.0625f);
      float p2 = __expf(acc[i][j][2] * 0.0625f);
      float p3 = __expf(acc[i][j][3] * 0.0625f);
      *(uint*)(Pp + (size_t)n * N_ + mbase) = pk4_e4m3(p0, p1, p2, p3);
      partial[j] += p0 + p1 + p2 + p3;
    }
  }
#pragma unroll
  for (int msk = 16; msk < 64; msk <<= 1)
#pragma unroll
    for (int j = 0; j < 4; j++)
      partial[j] += __shfl_xor(partial[j], msk);
  if (quad == 0) {
#pragma unroll
    for (int j = 0; j < 4; j++)
      atomicAdd(&rs[n0 + wn + j * 16 + lcol], partial[j]);
  }
}

// ---------------------------------------------------------------------------
// out (B,C,N) f32 = x + (V.P^T)/rowsum -- MX-fp8, K=2048, 128c x 128n
// mx_mainloop shape (R14-measured win): wave tile 64x64, MI=4, 16B
// LDS-read/MFMA. grid 512 = (16,4,8); b = Lf&7 XCD pin; rem&3 = c-tile so
// the 4 blocks sharing one P n-slab are dispatch-adjacent (slab L2-hot).
// ---------------------------------------------------------------------------
__global__ __launch_bounds__(256) void attn_o_kernel(
    const u8* __restrict__ V, const u8* __restrict__ P,
    const float* __restrict__ rowsum, const float* __restrict__ x,
    float* __restrict__ out)
{
  __shared__ __align__(16) u8 As[128][128], Bs[128][128];
  const int Lf = blockIdx.x +
                 (int)(gridDim.x * (blockIdx.y + gridDim.y * blockIdx.z));
  const int b = Lf & 7;
  const int rem = Lf >> 3;               // 0..63
  const int c0 = (rem & 3) * 128;        // adjacent blocks share P slab
  const int n0 = (rem >> 2) * 128;
  const u8* Ag = V + (size_t)b * C_ * N_ + (size_t)c0 * N_;    // rows c
  const u8* Bg = P + (size_t)b * N_ * N_ + (size_t)n0 * N_;    // rows n

  const f32x4 zero = {0.f, 0.f, 0.f, 0.f};
  f32x4 acc[4][4];
#pragma unroll
  for (int i = 0; i < 4; i++)
#pragma unroll
    for (int j = 0; j < 4; j++) acc[i][j] = zero;

  mx_mainloop(Ag, N_, Bg, N_, N_, As, Bs, acc);

  const int lane = threadIdx.x & 63;
  const int w = threadIdx.x >> 6;
  const int wm = (w >> 1) * 64, wn = (w & 1) * 64;
  const int quad = lane >> 4, lcol = lane & 15;

  const float* xb = x + (size_t)b * C_ * N_;
  float* ob = out + (size_t)b * C_ * N_;
  float invl[4];
#pragma unroll
  for (int j = 0; j < 4; j++)
    invl[j] = 1.f / rowsum[b * N_ + n0 + wn + j * 16 + lcol];

#pragma unroll
  for (int i = 0; i < 4; i++)
#pragma unroll
    for (int rr = 0; rr < 4; rr++) {
      int c = c0 + wm + i * 16 + quad * 4 + rr;
#pragma unroll
      for (int j = 0; j < 4; j++) {
        int n = n0 + wn + j * 16 + lcol;
        size_t idx = (size_t)c * N_ + n;
        ob[idx] = xb[idx] + acc[i][j][rr] * invl[j];
      }
    }
}

// ---------------------------------------------------------------------------
extern "C" void kernel_launch(void* const* d_in, const int* in_sizes, int n_in,
                              void* d_out, int out_size, void* d_ws, size_t ws_size,
                              hipStream_t stream)
{
  (void)in_sizes; (void)n_in; (void)out_size; (void)ws_size;
  const float* x  = (const float*)d_in[0];
  const float* Wq = (const float*)d_in[1];
  const float* bq = (const float*)d_in[2];
  const float* Wk = (const float*)d_in[3];
  const float* bk = (const float*)d_in[4];
  const float* Wv = (const float*)d_in[5];
  const float* bv = (const float*)d_in[6];
  float* out = (float*)d_out;

  char* ws = (char*)d_ws;
  size_t off = 0;
  auto carve = [&](size_t bytes) -> char* {
    char* p = ws + off;
    off += (bytes + 255) & ~(size_t)255;
    return p;
  };
  u8*  xT8  = (u8*) carve((size_t)B_ * N_ * C_);       // 8 MB fp8
  u8*  Wq8  = (u8*) carve((size_t)O_ * C_);
  u8*  Wk8  = (u8*) carve((size_t)O_ * C_);
  u8*  Wv8  = (u8*) carve((size_t)C_ * C_);
  u8*  Qt8  = (u8*) carve((size_t)B_ * N_ * O_);       // 4 MB fp8
  u8*  Kt8  = (u8*) carve((size_t)B_ * N_ * O_);       // 4 MB fp8
  u8*  Vb   = (u8*) carve((size_t)B_ * C_ * N_);       // 8 MB fp8
  u8*  P    = (u8*) carve((size_t)B_ * N_ * N_);       // 32 MB fp8
  float* rowsum = (float*)carve((size_t)B_ * N_ * 4);  // 64 KB

  prep_kernel<<<dim3(2560), 256, 0, stream>>>(
      x, Wq, Wk, Wv, xT8, Wq8, Wk8, Wv8, rowsum);
  proj_all_kernel<<<dim3(16, 8, 8), 256, 0, stream>>>(
      xT8, Wq8, bq, Wk8, bk, Wv8, bv, Qt8, Kt8, Vb);
  attn_s_kernel<<<dim3(8, 16, 8), 512, 0, stream>>>(Qt8, Kt8, P, rowsum);
  attn_o_kernel<<<dim3(16, 4, 8), 256, 0, stream>>>(Vb, P, rowsum, x, out);
}

// Round 18
// 164.306 us; speedup vs baseline: 1.0187x; 1.0187x over previous
//
#include <hip/hip_runtime.h>

#define B_ 8
#define C_ 512
#define N_ 2048
#define O_ 256   // C/2

typedef unsigned short u16;
typedef unsigned char u8;
typedef unsigned int uint;
typedef float f32x4 __attribute__((ext_vector_type(4)));
typedef int i32x8 __attribute__((ext_vector_type(8)));

#define AS1 __attribute__((address_space(1)))
#define AS3 __attribute__((address_space(3)))

__device__ __forceinline__ u16 f2bf(float f) {
  union { float f; unsigned u; } v; v.f = f;
  return (u16)((v.u + 0x7fffu + ((v.u >> 16) & 1u)) >> 16);  // RNE
}
__device__ __forceinline__ float bf2f(u16 h) {
  union { uint u; float f; } v; v.u = ((uint)h) << 16; return v.f;
}
// pack 4 floats -> 4 OCP e4m3 bytes (HW cvt, RNE)
__device__ __forceinline__ uint pk4_e4m3(float a, float b, float c, float d) {
  int r = __builtin_amdgcn_cvt_pk_fp8_f32(a, b, 0, false);
  r = __builtin_amdgcn_cvt_pk_fp8_f32(c, d, r, true);
  return (uint)r;
}

// ---------------------------------------------------------------------------
// 128x128 MX-fp8 tile main loop, K=128/instr, unit scales (verified r5-r7).
// Rows are lda/ldb BYTES. XOR 16B-group swizzle (row&7) on stage + read.
// acc[i][j]: row = wm+i*16+quad*4+rr, col = wn+j*16+(lane&15)
// Single-buffered 3-sync schedule: measured BEST (169 R0 / 167 R9 / 163 R14)
// vs explicit dbuf (177 R1) -- implicit multi-block overlap beats source
// pipelining. R17 lesson: 512-thr/48KB attn_s retile LOST 4us (2 blocks/CU
// vs 4) -- block-level TLP is the binding resource; do not enlarge lockstep
// domains. 16B LDS-read per MFMA.
// ---------------------------------------------------------------------------
union MxFrag { i32x8 v; uint4 q[2]; };

__device__ __forceinline__ void mx_mainloop(
    const u8* __restrict__ Ag, int lda,
    const u8* __restrict__ Bg, int ldb, int K,
    u8 (&As)[128][128], u8 (&Bs)[128][128], f32x4 (&acc)[4][4])
{
  const int t = threadIdx.x;
  const int lane = t & 63;
  const int w = t >> 6;
  const int wm = (w >> 1) * 64, wn = (w & 1) * 64;
  const int lrow = lane & 15, quad = lane >> 4;
  const int swz = lrow & 7;
  const int r8 = lane >> 3;
  const int gsrc = (lane & 7) ^ r8;

  for (int k0 = 0; k0 < K; k0 += 128) {
#pragma unroll
    for (int i = 0; i < 4; i++) {
      int row = i * 32 + w * 8;
      __builtin_amdgcn_global_load_lds(
          (const AS1 uint*)(Ag + (size_t)(row + r8) * lda + k0 + gsrc * 16),
          (AS3 uint*)(&As[row][0]), 16, 0, 0);
      __builtin_amdgcn_global_load_lds(
          (const AS1 uint*)(Bg + (size_t)(row + r8) * ldb + k0 + gsrc * 16),
          (AS3 uint*)(&Bs[row][0]), 16, 0, 0);
    }
    __syncthreads();
    const int g0 = (quad * 2) ^ swz, g1 = (quad * 2 + 1) ^ swz;
    MxFrag af[4], bfr[4];
#pragma unroll
    for (int i = 0; i < 4; i++) {
      const u8* rp = &As[wm + i * 16 + lrow][0];
      af[i].q[0] = *(const uint4*)(rp + g0 * 16);
      af[i].q[1] = *(const uint4*)(rp + g1 * 16);
    }
#pragma unroll
    for (int j = 0; j < 4; j++) {
      const u8* rp = &Bs[wn + j * 16 + lrow][0];
      bfr[j].q[0] = *(const uint4*)(rp + g0 * 16);
      bfr[j].q[1] = *(const uint4*)(rp + g1 * 16);
    }
#pragma unroll
    for (int i = 0; i < 4; i++)
#pragma unroll
      for (int j = 0; j < 4; j++)
        acc[i][j] = __builtin_amdgcn_mfma_scale_f32_16x16x128_f8f6f4(
            af[i].v, bfr[j].v, acc[i][j],
            0, 0,                      // fp8 e4m3 / fp8 e4m3
            0, 0x7f7f7f7f,             // A scales = 1.0
            0, 0x7f7f7f7f);            // B scales = 1.0
    __syncthreads();
  }
}

// ---------------------------------------------------------------------------
// prep: ONE dispatch does (a) x (B,C,N) f32 -> xT8 (B,N,C) fp8 via 64x64 LDS
// tile transpose (blocks 0..2047), (b) W fp32 -> fp8 (blocks 2048..2559),
// (c) rowsum zero-init. grid 2560 x 256 thr.
// ---------------------------------------------------------------------------
__global__ __launch_bounds__(256) void prep_kernel(
    const float* __restrict__ x,
    const float* __restrict__ Wq, const float* __restrict__ Wk,
    const float* __restrict__ Wv,
    u8* __restrict__ xT8, u8* __restrict__ Wq8, u8* __restrict__ Wk8,
    u8* __restrict__ Wv8, float* __restrict__ rowsum)
{
  __shared__ u16 tile[64][72];
  const int bid = blockIdx.x;
  const int t = threadIdx.x;
  if (bid < 2048) {
    int b = bid >> 8;
    int n0 = (bid & 31) * 64;
    int c0 = ((bid >> 5) & 7) * 64;
    const float* src = x + (size_t)b * C_ * N_ + (size_t)c0 * N_ + n0;
    int r = t >> 4;            // 0..15
    int f4 = (t & 15) * 4;     // 0..60 (n offset)
#pragma unroll
    for (int i = 0; i < 4; i++) {
      int c = r + 16 * i;
      float4 v = *(const float4*)(src + (size_t)c * N_ + f4);
      tile[f4 + 0][c] = f2bf(v.x);
      tile[f4 + 1][c] = f2bf(v.y);
      tile[f4 + 2][c] = f2bf(v.z);
      tile[f4 + 3][c] = f2bf(v.w);
    }
    __syncthreads();
    u8* dst = xT8 + (size_t)b * N_ * C_ + (size_t)n0 * C_ + c0;
    int n = t >> 2;            // 0..63
    int cc = (t & 3) * 16;     // 0,16,32,48
    uint4 d;
    d.x = pk4_e4m3(bf2f(tile[n][cc + 0]), bf2f(tile[n][cc + 1]),
                   bf2f(tile[n][cc + 2]), bf2f(tile[n][cc + 3]));
    d.y = pk4_e4m3(bf2f(tile[n][cc + 4]), bf2f(tile[n][cc + 5]),
                   bf2f(tile[n][cc + 6]), bf2f(tile[n][cc + 7]));
    d.z = pk4_e4m3(bf2f(tile[n][cc + 8]), bf2f(tile[n][cc + 9]),
                   bf2f(tile[n][cc + 10]), bf2f(tile[n][cc + 11]));
    d.w = pk4_e4m3(bf2f(tile[n][cc + 12]), bf2f(tile[n][cc + 13]),
                   bf2f(tile[n][cc + 14]), bf2f(tile[n][cc + 15]));
    *(uint4*)(dst + (size_t)n * C_ + cc) = d;
  } else {
    int gid = (bid - 2048) * 256 + t;      // 0..131071, 4 elems each
    const float* src; u8* dst; int o;
    if (gid < 32768)      { src = Wq; dst = Wq8; o = gid; }
    else if (gid < 65536) { src = Wk; dst = Wk8; o = gid - 32768; }
    else                  { src = Wv; dst = Wv8; o = gid - 65536; }
    float4 v = *(const float4*)(src + (size_t)o * 4);
    *(uint*)(dst + (size_t)o * 4) = pk4_e4m3(v.x, v.y, v.z, v.w);
    if (gid < 4096) {
      float4 z = {0.f, 0.f, 0.f, 0.f};
      *(float4*)(rowsum + gid * 4) = z;
    }
  }
}

// ---------------------------------------------------------------------------
// Unified projection (MX-fp8, K=512, 4 staging iters). grid 1024 = (16,8,8):
// XCD swizzle: b = L&7 pins batch->XCD.
//   sub 0..3: Q/K o-tiles -- transposed gemm A=W rows o, B=xT8 rows n,
//           rr walks o -> fp8 dword stores Qt8/Kt8[n][o..o+4)
//   sub 4..7: V c-tiles   -- A=xT8 rows n, B=Wv rows c,
//           rr walks n -> fp8 dword stores V8[c][n..n+4)
// ---------------------------------------------------------------------------
__global__ __launch_bounds__(256) void proj_all_kernel(
    const u8* __restrict__ xT8,
    const u8* __restrict__ Wq8, const float* __restrict__ bq,
    const u8* __restrict__ Wk8, const float* __restrict__ bk,
    const u8* __restrict__ Wv8, const float* __restrict__ bv,
    u8* __restrict__ Qt8, u8* __restrict__ Kt8, u8* __restrict__ V8)
{
  __shared__ __align__(16) u8 As[128][128], Bs[128][128];
  const int Lf = blockIdx.x +
                 (int)(gridDim.x * (blockIdx.y + gridDim.y * blockIdx.z));
  const int b = Lf & 7;                  // XCD = dispatch%8 heuristic
  const int rem = Lf >> 3;               // 0..127
  const int n0 = (rem & 15) * 128;
  const int sub = rem >> 4;              // 0..7
  const u8* xTb = xT8 + (size_t)b * N_ * C_ + (size_t)n0 * C_;

  const f32x4 zero = {0.f, 0.f, 0.f, 0.f};
  f32x4 acc[4][4];
#pragma unroll
  for (int i = 0; i < 4; i++)
#pragma unroll
    for (int j = 0; j < 4; j++) acc[i][j] = zero;

  const int lane = threadIdx.x & 63;
  const int w = threadIdx.x >> 6;
  const int wm = (w >> 1) * 64, wn = (w & 1) * 64;
  const int quad = lane >> 4, lcol = lane & 15;

  if (sub < 4) {
    const int isK = sub >> 1;
    const int o0 = (sub & 1) * 128;
    const u8* Wg = (isK ? Wk8 : Wq8) + (size_t)o0 * C_;
    const float* bias = isK ? bk : bq;
    u8* outp = (isK ? Kt8 : Qt8) + (size_t)b * N_ * O_;

    mx_mainloop(Wg, C_, xTb, C_, C_, As, Bs, acc);

#pragma unroll
    for (int i = 0; i < 4; i++) {
      int obase = o0 + wm + i * 16 + quad * 4;
      float4 bb = *(const float4*)(bias + obase);
#pragma unroll
      for (int j = 0; j < 4; j++) {
        int n = n0 + wn + j * 16 + lcol;
        uint d = pk4_e4m3(acc[i][j][0] + bb.x, acc[i][j][1] + bb.y,
                          acc[i][j][2] + bb.z, acc[i][j][3] + bb.w);
        *(uint*)(outp + (size_t)n * O_ + obase) = d;
      }
    }
  } else {
    const int c0 = (sub - 4) * 128;
    const u8* Wg = Wv8 + (size_t)c0 * C_;
    u8* outp = V8 + (size_t)b * C_ * N_;

    mx_mainloop(xTb, C_, Wg, C_, C_, As, Bs, acc);

#pragma unroll
    for (int j = 0; j < 4; j++) {
      int c = c0 + wn + j * 16 + lcol;
      float bb = bv[c];
#pragma unroll
      for (int i = 0; i < 4; i++) {
        int nbase = n0 + wm + i * 16 + quad * 4;
        uint d = pk4_e4m3(acc[i][j][0] + bb, acc[i][j][1] + bb,
                          acc[i][j][2] + bb, acc[i][j][3] + bb);
        *(uint*)(outp + (size_t)c * N_ + nbase) = d;
      }
    }
  }
}

// ---------------------------------------------------------------------------
// P (B,N,N) fp8 = exp(scale * Q.K^T), MX-fp8 (K=256). Transposed gemm
// T[m][n] = K.Q^T: rr walks m -> dword stores into P[n][:]. rowsum via
// quad-reduce + atomics. grid 2048 = (16,16,8); b = L&7 XCD-pins batch.
// (R14 shape restored -- R15/R17's 256m retile lost 4us to TLP reduction.)
// ---------------------------------------------------------------------------
__global__ __launch_bounds__(256) void attn_s_kernel(
    const u8* __restrict__ Qt8, const u8* __restrict__ Kt8,
    u8* __restrict__ P, float* __restrict__ rowsum)
{
  __shared__ __align__(16) u8 As[128][128], Bs[128][128];
  const int Lf = blockIdx.x +
                 (int)(gridDim.x * (blockIdx.y + gridDim.y * blockIdx.z));
  const int b = Lf & 7;
  const int rem = Lf >> 3;               // 0..255
  const int m0 = (rem & 15) * 128;
  const int n0 = (rem >> 4) * 128;
  const u8* Ag = Kt8 + (size_t)b * N_ * O_ + (size_t)m0 * O_;   // rows m
  const u8* Bg = Qt8 + (size_t)b * N_ * O_ + (size_t)n0 * O_;   // rows n

  const f32x4 zero = {0.f, 0.f, 0.f, 0.f};
  f32x4 acc[4][4];
#pragma unroll
  for (int i = 0; i < 4; i++)
#pragma unroll
    for (int j = 0; j < 4; j++) acc[i][j] = zero;

  mx_mainloop(Ag, O_, Bg, O_, O_, As, Bs, acc);

  u8* Pp = P + (size_t)b * N_ * N_;
  float* rs = rowsum + (size_t)b * N_;
  const int lane = threadIdx.x & 63;
  const int w = threadIdx.x >> 6;
  const int wm = (w >> 1) * 64, wn = (w & 1) * 64;
  const int quad = lane >> 4, lcol = lane & 15;

  float partial[4];
#pragma unroll
  for (int j = 0; j < 4; j++) partial[j] = 0.f;

#pragma unroll
  for (int j = 0; j < 4; j++) {
    int n = n0 + wn + j * 16 + lcol;
#pragma unroll
    for (int i = 0; i < 4; i++) {
      int mbase = m0 + wm + i * 16 + quad * 4;
      float p0 = __expf(acc[i][j][0] * 0.0625f);   // scale = 1/sqrt(256)
      float p1 = __expf(acc[i][j][1] * 0.0625f);
      float p2 = __expf(acc[i][j][2] * 0.0625f);
      float p3 = __expf(acc[i][j][3] * 0.0625f);
      *(uint*)(Pp + (size_t)n * N_ + mbase) = pk4_e4m3(p0, p1, p2, p3);
      partial[j] += p0 + p1 + p2 + p3;
    }
  }
#pragma unroll
  for (int msk = 16; msk < 64; msk <<= 1)
#pragma unroll
    for (int j = 0; j < 4; j++)
      partial[j] += __shfl_xor(partial[j], msk);
  if (quad == 0) {
#pragma unroll
    for (int j = 0; j < 4; j++)
      atomicAdd(&rs[n0 + wn + j * 16 + lcol], partial[j]);
  }
}

// ---------------------------------------------------------------------------
// out (B,C,N) f32 = x + (V.P^T)/rowsum -- MX-fp8, K=2048, 128c x 128n
// mx_mainloop shape (R14-measured win): wave tile 64x64, MI=4, 16B
// LDS-read/MFMA. grid 512 = (16,4,8); b = Lf&7 XCD pin; rem&3 = c-tile so
// the 4 blocks sharing one P n-slab are dispatch-adjacent (slab L2-hot).
// ---------------------------------------------------------------------------
__global__ __launch_bounds__(256) void attn_o_kernel(
    const u8* __restrict__ V, const u8* __restrict__ P,
    const float* __restrict__ rowsum, const float* __restrict__ x,
    float* __restrict__ out)
{
  __shared__ __align__(16) u8 As[128][128], Bs[128][128];
  const int Lf = blockIdx.x +
                 (int)(gridDim.x * (blockIdx.y + gridDim.y * blockIdx.z));
  const int b = Lf & 7;
  const int rem = Lf >> 3;               // 0..63
  const int c0 = (rem & 3) * 128;        // adjacent blocks share P slab
  const int n0 = (rem >> 2) * 128;
  const u8* Ag = V + (size_t)b * C_ * N_ + (size_t)c0 * N_;    // rows c
  const u8* Bg = P + (size_t)b * N_ * N_ + (size_t)n0 * N_;    // rows n

  const f32x4 zero = {0.f, 0.f, 0.f, 0.f};
  f32x4 acc[4][4];
#pragma unroll
  for (int i = 0; i < 4; i++)
#pragma unroll
    for (int j = 0; j < 4; j++) acc[i][j] = zero;

  mx_mainloop(Ag, N_, Bg, N_, N_, As, Bs, acc);

  const int lane = threadIdx.x & 63;
  const int w = threadIdx.x >> 6;
  const int wm = (w >> 1) * 64, wn = (w & 1) * 64;
  const int quad = lane >> 4, lcol = lane & 15;

  const float* xb = x + (size_t)b * C_ * N_;
  float* ob = out + (size_t)b * C_ * N_;
  float invl[4];
#pragma unroll
  for (int j = 0; j < 4; j++)
    invl[j] = 1.f / rowsum[b * N_ + n0 + wn + j * 16 + lcol];

#pragma unroll
  for (int i = 0; i < 4; i++)
#pragma unroll
    for (int rr = 0; rr < 4; rr++) {
      int c = c0 + wm + i * 16 + quad * 4 + rr;
#pragma unroll
      for (int j = 0; j < 4; j++) {
        int n = n0 + wn + j * 16 + lcol;
        size_t idx = (size_t)c * N_ + n;
        ob[idx] = xb[idx] + acc[i][j][rr] * invl[j];
      }
    }
}

// ---------------------------------------------------------------------------
extern "C" void kernel_launch(void* const* d_in, const int* in_sizes, int n_in,
                              void* d_out, int out_size, void* d_ws, size_t ws_size,
                              hipStream_t stream)
{
  (void)in_sizes; (void)n_in; (void)out_size; (void)ws_size;
  const float* x  = (const float*)d_in[0];
  const float* Wq = (const float*)d_in[1];
  const float* bq = (const float*)d_in[2];
  const float* Wk = (const float*)d_in[3];
  const float* bk = (const float*)d_in[4];
  const float* Wv = (const float*)d_in[5];
  const float* bv = (const float*)d_in[6];
  float* out = (float*)d_out;

  char* ws = (char*)d_ws;
  size_t off = 0;
  auto carve = [&](size_t bytes) -> char* {
    char* p = ws + off;
    off += (bytes + 255) & ~(size_t)255;
    return p;
  };
  u8*  xT8  = (u8*) carve((size_t)B_ * N_ * C_);       // 8 MB fp8
  u8*  Wq8  = (u8*) carve((size_t)O_ * C_);
  u8*  Wk8  = (u8*) carve((size_t)O_ * C_);
  u8*  Wv8  = (u8*) carve((size_t)C_ * C_);
  u8*  Qt8  = (u8*) carve((size_t)B_ * N_ * O_);       // 4 MB fp8
  u8*  Kt8  = (u8*) carve((size_t)B_ * N_ * O_);       // 4 MB fp8
  u8*  Vb   = (u8*) carve((size_t)B_ * C_ * N_);       // 8 MB fp8
  u8*  P    = (u8*) carve((size_t)B_ * N_ * N_);       // 32 MB fp8
  float* rowsum = (float*)carve((size_t)B_ * N_ * 4);  // 64 KB

  prep_kernel<<<dim3(2560), 256, 0, stream>>>(
      x, Wq, Wk, Wv, xT8, Wq8, Wk8, Wv8, rowsum);
  proj_all_kernel<<<dim3(16, 8, 8), 256, 0, stream>>>(
      xT8, Wq8, bq, Wk8, bk, Wv8, bv, Qt8, Kt8, Vb);
  attn_s_kernel<<<dim3(16, 16, 8), 256, 0, stream>>>(Qt8, Kt8, P, rowsum);
  attn_o_kernel<<<dim3(16, 4, 8), 256, 0, stream>>>(Vb, P, rowsum, x, out);
}

// Round 19
// 161.174 us; speedup vs baseline: 1.0385x; 1.0194x over previous
//
#include <hip/hip_runtime.h>

#define B_ 8
#define C_ 512
#define N_ 2048
#define O_ 256   // C/2

typedef unsigned short u16;
typedef unsigned char u8;
typedef unsigned int uint;
typedef float f32x4 __attribute__((ext_vector_type(4)));
typedef int i32x8 __attribute__((ext_vector_type(8)));

#define AS1 __attribute__((address_space(1)))
#define AS3 __attribute__((address_space(3)))

__device__ __forceinline__ u16 f2bf(float f) {
  union { float f; unsigned u; } v; v.f = f;
  return (u16)((v.u + 0x7fffu + ((v.u >> 16) & 1u)) >> 16);  // RNE
}
__device__ __forceinline__ float bf2f(u16 h) {
  union { uint u; float f; } v; v.u = ((uint)h) << 16; return v.f;
}
// pack 4 floats -> 4 OCP e4m3 bytes (HW cvt, RNE)
__device__ __forceinline__ uint pk4_e4m3(float a, float b, float c, float d) {
  int r = __builtin_amdgcn_cvt_pk_fp8_f32(a, b, 0, false);
  r = __builtin_amdgcn_cvt_pk_fp8_f32(c, d, r, true);
  return (uint)r;
}

// ---------------------------------------------------------------------------
// 128x128 MX-fp8 tile main loop, K=128/instr, unit scales (verified r5-r7).
// Rows are lda/ldb BYTES. XOR 16B-group swizzle (row&7) on stage + read.
// acc[i][j]: row = wm+i*16+quad*4+rr, col = wn+j*16+(lane&15)
// Single-buffered 3-sync schedule: measured BEST (R14/R18 = 163.2/164.3)
// vs explicit dbuf (177 R1). R17 lesson: enlarging the lockstep domain
// (512-thr blocks) cut resident blocks/CU and LOST 4us -- block TLP is the
// binding resource; only change per-block efficiency at CONSTANT residency.
// ---------------------------------------------------------------------------
union MxFrag { i32x8 v; uint4 q[2]; };

__device__ __forceinline__ void mx_mainloop(
    const u8* __restrict__ Ag, int lda,
    const u8* __restrict__ Bg, int ldb, int K,
    u8 (&As)[128][128], u8 (&Bs)[128][128], f32x4 (&acc)[4][4])
{
  const int t = threadIdx.x;
  const int lane = t & 63;
  const int w = t >> 6;
  const int wm = (w >> 1) * 64, wn = (w & 1) * 64;
  const int lrow = lane & 15, quad = lane >> 4;
  const int swz = lrow & 7;
  const int r8 = lane >> 3;
  const int gsrc = (lane & 7) ^ r8;

  for (int k0 = 0; k0 < K; k0 += 128) {
#pragma unroll
    for (int i = 0; i < 4; i++) {
      int row = i * 32 + w * 8;
      __builtin_amdgcn_global_load_lds(
          (const AS1 uint*)(Ag + (size_t)(row + r8) * lda + k0 + gsrc * 16),
          (AS3 uint*)(&As[row][0]), 16, 0, 0);
      __builtin_amdgcn_global_load_lds(
          (const AS1 uint*)(Bg + (size_t)(row + r8) * ldb + k0 + gsrc * 16),
          (AS3 uint*)(&Bs[row][0]), 16, 0, 0);
    }
    __syncthreads();
    const int g0 = (quad * 2) ^ swz, g1 = (quad * 2 + 1) ^ swz;
    MxFrag af[4], bfr[4];
#pragma unroll
    for (int i = 0; i < 4; i++) {
      const u8* rp = &As[wm + i * 16 + lrow][0];
      af[i].q[0] = *(const uint4*)(rp + g0 * 16);
      af[i].q[1] = *(const uint4*)(rp + g1 * 16);
    }
#pragma unroll
    for (int j = 0; j < 4; j++) {
      const u8* rp = &Bs[wn + j * 16 + lrow][0];
      bfr[j].q[0] = *(const uint4*)(rp + g0 * 16);
      bfr[j].q[1] = *(const uint4*)(rp + g1 * 16);
    }
#pragma unroll
    for (int i = 0; i < 4; i++)
#pragma unroll
      for (int j = 0; j < 4; j++)
        acc[i][j] = __builtin_amdgcn_mfma_scale_f32_16x16x128_f8f6f4(
            af[i].v, bfr[j].v, acc[i][j],
            0, 0,                      // fp8 e4m3 / fp8 e4m3
            0, 0x7f7f7f7f,             // A scales = 1.0
            0, 0x7f7f7f7f);            // B scales = 1.0
    __syncthreads();
  }
}

// ---------------------------------------------------------------------------
// prep: ONE dispatch does (a) x (B,C,N) f32 -> xT8 (B,N,C) fp8 via 64x64 LDS
// tile transpose (blocks 0..2047), (b) W fp32 -> fp8 (blocks 2048..2559),
// (c) rowsum zero-init. grid 2560 x 256 thr.
// ---------------------------------------------------------------------------
__global__ __launch_bounds__(256) void prep_kernel(
    const float* __restrict__ x,
    const float* __restrict__ Wq, const float* __restrict__ Wk,
    const float* __restrict__ Wv,
    u8* __restrict__ xT8, u8* __restrict__ Wq8, u8* __restrict__ Wk8,
    u8* __restrict__ Wv8, float* __restrict__ rowsum)
{
  __shared__ u16 tile[64][72];
  const int bid = blockIdx.x;
  const int t = threadIdx.x;
  if (bid < 2048) {
    int b = bid >> 8;
    int n0 = (bid & 31) * 64;
    int c0 = ((bid >> 5) & 7) * 64;
    const float* src = x + (size_t)b * C_ * N_ + (size_t)c0 * N_ + n0;
    int r = t >> 4;            // 0..15
    int f4 = (t & 15) * 4;     // 0..60 (n offset)
#pragma unroll
    for (int i = 0; i < 4; i++) {
      int c = r + 16 * i;
      float4 v = *(const float4*)(src + (size_t)c * N_ + f4);
      tile[f4 + 0][c] = f2bf(v.x);
      tile[f4 + 1][c] = f2bf(v.y);
      tile[f4 + 2][c] = f2bf(v.z);
      tile[f4 + 3][c] = f2bf(v.w);
    }
    __syncthreads();
    u8* dst = xT8 + (size_t)b * N_ * C_ + (size_t)n0 * C_ + c0;
    int n = t >> 2;            // 0..63
    int cc = (t & 3) * 16;     // 0,16,32,48
    uint4 d;
    d.x = pk4_e4m3(bf2f(tile[n][cc + 0]), bf2f(tile[n][cc + 1]),
                   bf2f(tile[n][cc + 2]), bf2f(tile[n][cc + 3]));
    d.y = pk4_e4m3(bf2f(tile[n][cc + 4]), bf2f(tile[n][cc + 5]),
                   bf2f(tile[n][cc + 6]), bf2f(tile[n][cc + 7]));
    d.z = pk4_e4m3(bf2f(tile[n][cc + 8]), bf2f(tile[n][cc + 9]),
                   bf2f(tile[n][cc + 10]), bf2f(tile[n][cc + 11]));
    d.w = pk4_e4m3(bf2f(tile[n][cc + 12]), bf2f(tile[n][cc + 13]),
                   bf2f(tile[n][cc + 14]), bf2f(tile[n][cc + 15]));
    *(uint4*)(dst + (size_t)n * C_ + cc) = d;
  } else {
    int gid = (bid - 2048) * 256 + t;      // 0..131071, 4 elems each
    const float* src; u8* dst; int o;
    if (gid < 32768)      { src = Wq; dst = Wq8; o = gid; }
    else if (gid < 65536) { src = Wk; dst = Wk8; o = gid - 32768; }
    else                  { src = Wv; dst = Wv8; o = gid - 65536; }
    float4 v = *(const float4*)(src + (size_t)o * 4);
    *(uint*)(dst + (size_t)o * 4) = pk4_e4m3(v.x, v.y, v.z, v.w);
    if (gid < 4096) {
      float4 z = {0.f, 0.f, 0.f, 0.f};
      *(float4*)(rowsum + gid * 4) = z;
    }
  }
}

// ---------------------------------------------------------------------------
// Unified projection (MX-fp8, K=512, 4 staging iters). grid 1024 = (16,8,8):
// XCD swizzle: b = L&7 pins batch->XCD.
//   sub 0..3: Q/K o-tiles -- transposed gemm A=W rows o, B=xT8 rows n,
//           rr walks o -> fp8 dword stores Qt8/Kt8[n][o..o+4)
//   sub 4..7: V c-tiles   -- A=xT8 rows n, B=Wv rows c,
//           rr walks n -> fp8 dword stores V8[c][n..n+4)
// ---------------------------------------------------------------------------
__global__ __launch_bounds__(256) void proj_all_kernel(
    const u8* __restrict__ xT8,
    const u8* __restrict__ Wq8, const float* __restrict__ bq,
    const u8* __restrict__ Wk8, const float* __restrict__ bk,
    const u8* __restrict__ Wv8, const float* __restrict__ bv,
    u8* __restrict__ Qt8, u8* __restrict__ Kt8, u8* __restrict__ V8)
{
  __shared__ __align__(16) u8 As[128][128], Bs[128][128];
  const int Lf = blockIdx.x +
                 (int)(gridDim.x * (blockIdx.y + gridDim.y * blockIdx.z));
  const int b = Lf & 7;                  // XCD = dispatch%8 heuristic
  const int rem = Lf >> 3;               // 0..127
  const int n0 = (rem & 15) * 128;
  const int sub = rem >> 4;              // 0..7
  const u8* xTb = xT8 + (size_t)b * N_ * C_ + (size_t)n0 * C_;

  const f32x4 zero = {0.f, 0.f, 0.f, 0.f};
  f32x4 acc[4][4];
#pragma unroll
  for (int i = 0; i < 4; i++)
#pragma unroll
    for (int j = 0; j < 4; j++) acc[i][j] = zero;

  const int lane = threadIdx.x & 63;
  const int w = threadIdx.x >> 6;
  const int wm = (w >> 1) * 64, wn = (w & 1) * 64;
  const int quad = lane >> 4, lcol = lane & 15;

  if (sub < 4) {
    const int isK = sub >> 1;
    const int o0 = (sub & 1) * 128;
    const u8* Wg = (isK ? Wk8 : Wq8) + (size_t)o0 * C_;
    const float* bias = isK ? bk : bq;
    u8* outp = (isK ? Kt8 : Qt8) + (size_t)b * N_ * O_;

    mx_mainloop(Wg, C_, xTb, C_, C_, As, Bs, acc);

#pragma unroll
    for (int i = 0; i < 4; i++) {
      int obase = o0 + wm + i * 16 + quad * 4;
      float4 bb = *(const float4*)(bias + obase);
#pragma unroll
      for (int j = 0; j < 4; j++) {
        int n = n0 + wn + j * 16 + lcol;
        uint d = pk4_e4m3(acc[i][j][0] + bb.x, acc[i][j][1] + bb.y,
                          acc[i][j][2] + bb.z, acc[i][j][3] + bb.w);
        *(uint*)(outp + (size_t)n * O_ + obase) = d;
      }
    }
  } else {
    const int c0 = (sub - 4) * 128;
    const u8* Wg = Wv8 + (size_t)c0 * C_;
    u8* outp = V8 + (size_t)b * C_ * N_;

    mx_mainloop(xTb, C_, Wg, C_, C_, As, Bs, acc);

#pragma unroll
    for (int j = 0; j < 4; j++) {
      int c = c0 + wn + j * 16 + lcol;
      float bb = bv[c];
#pragma unroll
      for (int i = 0; i < 4; i++) {
        int nbase = n0 + wm + i * 16 + quad * 4;
        uint d = pk4_e4m3(acc[i][j][0] + bb, acc[i][j][1] + bb,
                          acc[i][j][2] + bb, acc[i][j][3] + bb);
        *(uint*)(outp + (size_t)c * N_ + nbase) = d;
      }
    }
  }
}

// ---------------------------------------------------------------------------
// P (B,N,N) fp8 = exp(scale * Q.K^T), MX-fp8 (K=256). Transposed gemm
// T[m][n] = K.Q^T: rr walks m -> dword stores into P[n][:]. rowsum via
// quad-reduce + atomics. grid 2048 = (16,16,8); b = L&7 XCD-pins batch.
// (R14 shape -- R15/R17's 256m retile lost 4us to TLP reduction.)
// ---------------------------------------------------------------------------
__global__ __launch_bounds__(256) void attn_s_kernel(
    const u8* __restrict__ Qt8, const u8* __restrict__ Kt8,
    u8* __restrict__ P, float* __restrict__ rowsum)
{
  __shared__ __align__(16) u8 As[128][128], Bs[128][128];
  const int Lf = blockIdx.x +
                 (int)(gridDim.x * (blockIdx.y + gridDim.y * blockIdx.z));
  const int b = Lf & 7;
  const int rem = Lf >> 3;               // 0..255
  const int m0 = (rem & 15) * 128;
  const int n0 = (rem >> 4) * 128;
  const u8* Ag = Kt8 + (size_t)b * N_ * O_ + (size_t)m0 * O_;   // rows m
  const u8* Bg = Qt8 + (size_t)b * N_ * O_ + (size_t)n0 * O_;   // rows n

  const f32x4 zero = {0.f, 0.f, 0.f, 0.f};
  f32x4 acc[4][4];
#pragma unroll
  for (int i = 0; i < 4; i++)
#pragma unroll
    for (int j = 0; j < 4; j++) acc[i][j] = zero;

  mx_mainloop(Ag, O_, Bg, O_, O_, As, Bs, acc);

  u8* Pp = P + (size_t)b * N_ * N_;
  float* rs = rowsum + (size_t)b * N_;
  const int lane = threadIdx.x & 63;
  const int w = threadIdx.x >> 6;
  const int wm = (w >> 1) * 64, wn = (w & 1) * 64;
  const int quad = lane >> 4, lcol = lane & 15;

  float partial[4];
#pragma unroll
  for (int j = 0; j < 4; j++) partial[j] = 0.f;

#pragma unroll
  for (int j = 0; j < 4; j++) {
    int n = n0 + wn + j * 16 + lcol;
#pragma unroll
    for (int i = 0; i < 4; i++) {
      int mbase = m0 + wm + i * 16 + quad * 4;
      float p0 = __expf(acc[i][j][0] * 0.0625f);   // scale = 1/sqrt(256)
      float p1 = __expf(acc[i][j][1] * 0.0625f);
      float p2 = __expf(acc[i][j][2] * 0.0625f);
      float p3 = __expf(acc[i][j][3] * 0.0625f);
      *(uint*)(Pp + (size_t)n * N_ + mbase) = pk4_e4m3(p0, p1, p2, p3);
      partial[j] += p0 + p1 + p2 + p3;
    }
  }
#pragma unroll
  for (int msk = 16; msk < 64; msk <<= 1)
#pragma unroll
    for (int j = 0; j < 4; j++)
      partial[j] += __shfl_xor(partial[j], msk);
  if (quad == 0) {
#pragma unroll
    for (int j = 0; j < 4; j++)
      atomicAdd(&rs[n0 + wn + j * 16 + lcol], partial[j]);
  }
}

// ---------------------------------------------------------------------------
// out (B,C,N) f32 = x + (V.P^T)/rowsum -- MX-fp8, K=2048, 128c x 128n tile.
// R19: 2 K-chunks per barrier pair (split buffers, 64 KB LDS). attn_o's
// grid is 2 blocks/CU and 160/64=2 fit -> residency UNCHANGED while sync
// count halves (32 -> 16 per block) and each drain amortizes 16 loads.
// Chunk compute order k0, k0+128 preserved -> bitwise-identical output.
// grid 512 = (16,4,8); b = Lf&7 XCD pin; rem&3 = c-tile (P slab adjacency).
// ---------------------------------------------------------------------------
__global__ __launch_bounds__(256) void attn_o_kernel(
    const u8* __restrict__ V, const u8* __restrict__ P,
    const float* __restrict__ rowsum, const float* __restrict__ x,
    float* __restrict__ out)
{
  __shared__ __align__(16) u8 As[2][128][128], Bs[2][128][128];  // 64 KB
  const int Lf = blockIdx.x +
                 (int)(gridDim.x * (blockIdx.y + gridDim.y * blockIdx.z));
  const int b = Lf & 7;
  const int rem = Lf >> 3;               // 0..63
  const int c0 = (rem & 3) * 128;        // adjacent blocks share P slab
  const int n0 = (rem >> 2) * 128;
  const u8* Ag = V + (size_t)b * C_ * N_ + (size_t)c0 * N_;    // rows c
  const u8* Bg = P + (size_t)b * N_ * N_ + (size_t)n0 * N_;    // rows n

  const int t = threadIdx.x;
  const int lane = t & 63;
  const int w = t >> 6;
  const int wm = (w >> 1) * 64, wn = (w & 1) * 64;
  const int lrow = lane & 15, quad = lane >> 4;
  const int swz = lrow & 7;
  const int r8 = lane >> 3;
  const int gsrc = (lane & 7) ^ r8;

  const f32x4 zero = {0.f, 0.f, 0.f, 0.f};
  f32x4 acc[4][4];
#pragma unroll
  for (int i = 0; i < 4; i++)
#pragma unroll
    for (int j = 0; j < 4; j++) acc[i][j] = zero;

  for (int k0 = 0; k0 < N_; k0 += 256) {
#pragma unroll
    for (int hb = 0; hb < 2; hb++) {
      const int kk = k0 + hb * 128;
#pragma unroll
      for (int i = 0; i < 4; i++) {
        int row = i * 32 + w * 8;
        __builtin_amdgcn_global_load_lds(
            (const AS1 uint*)(Ag + (size_t)(row + r8) * N_ + kk + gsrc * 16),
            (AS3 uint*)(&As[hb][row][0]), 16, 0, 0);
        __builtin_amdgcn_global_load_lds(
            (const AS1 uint*)(Bg + (size_t)(row + r8) * N_ + kk + gsrc * 16),
            (AS3 uint*)(&Bs[hb][row][0]), 16, 0, 0);
      }
    }
    __syncthreads();
    const int g0 = (quad * 2) ^ swz, g1 = (quad * 2 + 1) ^ swz;
#pragma unroll
    for (int hb = 0; hb < 2; hb++) {
      MxFrag af[4], bfr[4];
#pragma unroll
      for (int i = 0; i < 4; i++) {
        const u8* rp = &As[hb][wm + i * 16 + lrow][0];
        af[i].q[0] = *(const uint4*)(rp + g0 * 16);
        af[i].q[1] = *(const uint4*)(rp + g1 * 16);
      }
#pragma unroll
      for (int j = 0; j < 4; j++) {
        const u8* rp = &Bs[hb][wn + j * 16 + lrow][0];
        bfr[j].q[0] = *(const uint4*)(rp + g0 * 16);
        bfr[j].q[1] = *(const uint4*)(rp + g1 * 16);
      }
#pragma unroll
      for (int i = 0; i < 4; i++)
#pragma unroll
        for (int j = 0; j < 4; j++)
          acc[i][j] = __builtin_amdgcn_mfma_scale_f32_16x16x128_f8f6f4(
              af[i].v, bfr[j].v, acc[i][j],
              0, 0, 0, 0x7f7f7f7f, 0, 0x7f7f7f7f);
    }
    __syncthreads();
  }

  const int lcol = lane & 15;
  const float* xb = x + (size_t)b * C_ * N_;
  float* ob = out + (size_t)b * C_ * N_;
  float invl[4];
#pragma unroll
  for (int j = 0; j < 4; j++)
    invl[j] = 1.f / rowsum[b * N_ + n0 + wn + j * 16 + lcol];

#pragma unroll
  for (int i = 0; i < 4; i++)
#pragma unroll
    for (int rr = 0; rr < 4; rr++) {
      int c = c0 + wm + i * 16 + quad * 4 + rr;
#pragma unroll
      for (int j = 0; j < 4; j++) {
        int n = n0 + wn + j * 16 + lcol;
        size_t idx = (size_t)c * N_ + n;
        ob[idx] = xb[idx] + acc[i][j][rr] * invl[j];
      }
    }
}

// ---------------------------------------------------------------------------
extern "C" void kernel_launch(void* const* d_in, const int* in_sizes, int n_in,
                              void* d_out, int out_size, void* d_ws, size_t ws_size,
                              hipStream_t stream)
{
  (void)in_sizes; (void)n_in; (void)out_size; (void)ws_size;
  const float* x  = (const float*)d_in[0];
  const float* Wq = (const float*)d_in[1];
  const float* bq = (const float*)d_in[2];
  const float* Wk = (const float*)d_in[3];
  const float* bk = (const float*)d_in[4];
  const float* Wv = (const float*)d_in[5];
  const float* bv = (const float*)d_in[6];
  float* out = (float*)d_out;

  char* ws = (char*)d_ws;
  size_t off = 0;
  auto carve = [&](size_t bytes) -> char* {
    char* p = ws + off;
    off += (bytes + 255) & ~(size_t)255;
    return p;
  };
  u8*  xT8  = (u8*) carve((size_t)B_ * N_ * C_);       // 8 MB fp8
  u8*  Wq8  = (u8*) carve((size_t)O_ * C_);
  u8*  Wk8  = (u8*) carve((size_t)O_ * C_);
  u8*  Wv8  = (u8*) carve((size_t)C_ * C_);
  u8*  Qt8  = (u8*) carve((size_t)B_ * N_ * O_);       // 4 MB fp8
  u8*  Kt8  = (u8*) carve((size_t)B_ * N_ * O_);       // 4 MB fp8
  u8*  Vb   = (u8*) carve((size_t)B_ * C_ * N_);       // 8 MB fp8
  u8*  P    = (u8*) carve((size_t)B_ * N_ * N_);       // 32 MB fp8
  float* rowsum = (float*)carve((size_t)B_ * N_ * 4);  // 64 KB

  prep_kernel<<<dim3(2560), 256, 0, stream>>>(
      x, Wq, Wk, Wv, xT8, Wq8, Wk8, Wv8, rowsum);
  proj_all_kernel<<<dim3(16, 8, 8), 256, 0, stream>>>(
      xT8, Wq8, bq, Wk8, bk, Wv8, bv, Qt8, Kt8, Vb);
  attn_s_kernel<<<dim3(16, 16, 8), 256, 0, stream>>>(Qt8, Kt8, P, rowsum);
  attn_o_kernel<<<dim3(16, 4, 8), 256, 0, stream>>>(Vb, P, rowsum, x, out);
}